// Round 2
// 290.751 us; speedup vs baseline: 1.0325x; 1.0325x over previous
//
#include <hip/hip_runtime.h>

#define T_DIM 16384
#define B_DIM 64
#define E_DIM 4096
#define NBLK  1024
#define CHUNK 16   // rows per block (T_DIM / NBLK)

typedef float f32x4 __attribute__((ext_vector_type(4)));

// ---------------------------------------------------------------------------
// K1: per block of 16 rows: coeff sums (wave per 4 rows, ILP-4 gathers),
//     local inclusive scan of the 16 (a,b) pairs, write per-row local scans
//     (lab) and the block aggregate (agg).
// Compose (matches reference): state' = a*state + b =>
//   inclusive: B = a_j*B + b_j ; A = a_j*A   (B update uses old B only).
// ---------------------------------------------------------------------------
__global__ __launch_bounds__(256) void coeff_scan_kernel(
    const int*   __restrict__ indices,   // (T, B) int32
    const float* __restrict__ params,    // (N, 2)
    float2*      __restrict__ lab,       // [T] local inclusive scans
    float2*      __restrict__ agg)       // [NBLK] block aggregates
{
    __shared__ float sA[CHUNK], sB[CHUNK];
    const int tid   = threadIdx.x;
    const int lane  = tid & 63;
    const int wave  = tid >> 6;          // 0..3
    const int blk   = blockIdx.x;
    const int tbase = blk * CHUNK;
    const float2* __restrict__ P2 = (const float2*)params;

    const int j0 = wave * 4;             // this wave's 4 rows
    int i0 = indices[((tbase + j0 + 0) << 6) + lane];
    int i1 = indices[((tbase + j0 + 1) << 6) + lane];
    int i2 = indices[((tbase + j0 + 2) << 6) + lane];
    int i3 = indices[((tbase + j0 + 3) << 6) + lane];
    float2 p0 = P2[i0], p1 = P2[i1], p2 = P2[i2], p3 = P2[i3];
    float a0 = p0.x, b0 = p0.y, a1 = p1.x, b1 = p1.y;
    float a2 = p2.x, b2 = p2.y, a3 = p3.x, b3 = p3.y;
    #pragma unroll
    for (int off = 32; off >= 1; off >>= 1) {
        a0 += __shfl_down(a0, off, 64);  b0 += __shfl_down(b0, off, 64);
        a1 += __shfl_down(a1, off, 64);  b1 += __shfl_down(b1, off, 64);
        a2 += __shfl_down(a2, off, 64);  b2 += __shfl_down(b2, off, 64);
        a3 += __shfl_down(a3, off, 64);  b3 += __shfl_down(b3, off, 64);
    }
    if (lane == 0) {
        sA[j0+0] = a0; sB[j0+0] = b0;
        sA[j0+1] = a1; sB[j0+1] = b1;
        sA[j0+2] = a2; sB[j0+2] = b2;
        sA[j0+3] = a3; sB[j0+3] = b3;
    }
    __syncthreads();

    if (tid == 0) {
        float a = 1.0f, b = 0.0f;
        #pragma unroll
        for (int j = 0; j < CHUNK; ++j) {
            float aj = sA[j], bj = sB[j];
            b = aj * b + bj;             // old b only
            a = aj * a;
            sA[j] = a; sB[j] = b;
        }
        agg[blk] = make_float2(a, b);
    }
    __syncthreads();
    if (tid < CHUNK) lab[tbase + tid] = make_float2(sA[tid], sB[tid]);
}

// ---------------------------------------------------------------------------
// K2: one wave scans the 1024 block aggregates -> exclusive block prefixes.
// 16 aggregates per lane (serial) + 6-step shuffle scan across 64 lanes.
// ---------------------------------------------------------------------------
__global__ __launch_bounds__(64) void scan_agg_kernel(
    const float2* __restrict__ agg,      // [NBLK]
    float2*       __restrict__ pref)     // [NBLK] exclusive prefixes
{
    const int lane = threadIdx.x;        // 0..63
    const int base = lane * 16;
    float ca[16], cb[16];
    float a = 1.0f, b = 0.0f;
    #pragma unroll
    for (int i = 0; i < 16; ++i) {
        float2 g = agg[base + i];
        b = g.x * b + g.y;
        a = g.x * a;
        ca[i] = a; cb[i] = b;
    }
    // inclusive shuffle scan across 64 lane aggregates
    #pragma unroll
    for (int off = 1; off < 64; off <<= 1) {
        float pa = __shfl_up(a, off, 64);
        float pb = __shfl_up(b, off, 64);
        if (lane >= off) {
            float nb = a * pb + b;       // uses OLD a
            a = a * pa;
            b = nb;
        }
    }
    // exclusive lane prefix (aggregate of all earlier lanes' segments)
    float ea = __shfl_up(a, 1, 64);
    float eb = __shfl_up(b, 1, 64);
    if (lane == 0) { ea = 1.0f; eb = 0.0f; }
    pref[base] = make_float2(ea, eb);
    #pragma unroll
    for (int i = 1; i < 16; ++i) {
        pref[base + i] = make_float2(ca[i-1] * ea, ca[i-1] * eb + cb[i-1]);
    }
}

// ---------------------------------------------------------------------------
// K3: per block of 16 rows: out[t,e] = (la*Pa)*M[e] + (la*Pb + lb).
// M held in 4 float4 registers per thread; nontemporal streaming stores.
// ---------------------------------------------------------------------------
__global__ __launch_bounds__(256) void out_kernel(
    const float2* __restrict__ lab,
    const float2* __restrict__ pref,
    const float*  __restrict__ M,
    float*        __restrict__ out)
{
    __shared__ float2 s[CHUNK];
    const int tid   = threadIdx.x;
    const int blk   = blockIdx.x;
    const int tbase = blk * CHUNK;
    if (tid < CHUNK) s[tid] = lab[tbase + tid];
    const float2 P = pref[blk];
    const f32x4* __restrict__ M4 = (const f32x4*)M;
    f32x4 m0 = M4[tid], m1 = M4[tid + 256], m2 = M4[tid + 512], m3 = M4[tid + 768];
    __syncthreads();
    #pragma unroll
    for (int j = 0; j < CHUNK; ++j) {
        const float la = s[j].x, lb = s[j].y;
        const float At = la * P.x;
        const float Bt = la * P.y + lb;
        f32x4* __restrict__ O4 = (f32x4*)(out + (size_t)(tbase + j) * E_DIM);
        f32x4 r;
        r = At * m0 + Bt;  __builtin_nontemporal_store(r, &O4[tid      ]);
        r = At * m1 + Bt;  __builtin_nontemporal_store(r, &O4[tid + 256]);
        r = At * m2 + Bt;  __builtin_nontemporal_store(r, &O4[tid + 512]);
        r = At * m3 + Bt;  __builtin_nontemporal_store(r, &O4[tid + 768]);
    }
}

extern "C" void kernel_launch(void* const* d_in, const int* in_sizes, int n_in,
                              void* d_out, int out_size, void* d_ws, size_t ws_size,
                              hipStream_t stream) {
    const int*   indices = (const int*)d_in[0];     // (T, B) int32 on device
    const float* M_prev  = (const float*)d_in[1];   // (E,)
    const float* params  = (const float*)d_in[2];   // (N, 2)
    float* out = (float*)d_out;

    float2* lab  = (float2*)d_ws;                   // [T_DIM]
    float2* agg  = lab + T_DIM;                     // [NBLK]
    float2* pref = agg + NBLK;                      // [NBLK]

    coeff_scan_kernel<<<NBLK, 256, 0, stream>>>(indices, params, lab, agg);
    scan_agg_kernel<<<1, 64, 0, stream>>>(agg, pref);
    out_kernel<<<NBLK, 256, 0, stream>>>(lab, pref, M_prev, out);
}